// Round 1
// baseline (1013.519 us; speedup 1.0000x reference)
//
#include <hip/hip_runtime.h>
#include <stdint.h>

#define V_ELEMS (64*64*64)

typedef _Float16 f16x8 __attribute__((ext_vector_type(8)));
typedef _Float16 f16x4 __attribute__((ext_vector_type(4)));
typedef float f32x4 __attribute__((ext_vector_type(4)));

// LDS layout (bytes):
//   h  : [64][200] f16 @ 0      (25600)  token-major window input
//   q  : [2][64][40] f16 @ 25600 (10240) \ aliased by P [2][64][72] (18432)
//   k  : [2][64][40] f16 @ 35840 (10240) /
//   vt : [2][32][72] f16 @ 46080 (9216)  aliased by oh [64][72] (9216)
#define SMEM_BYTES 55296
#define H_STRIDE 200
#define QK_STRIDE 40
#define P_STRIDE 72
#define VT_STRIDE 72
#define OH_STRIDE 72

__global__ __launch_bounds__(256, 2)
void win_attn_kernel(const float* __restrict__ x,
                     const float* __restrict__ qkv_w,
                     const float* __restrict__ qkv_b,
                     const float* __restrict__ proj_w,
                     const float* __restrict__ proj_b,
                     float* __restrict__ out)
{
    extern __shared__ char smem[];
    _Float16* h_s  = (_Float16*)smem;                    // [64][200]
    _Float16* q_s  = (_Float16*)(smem + 25600);          // [2][64][40]
    _Float16* k_s  = (_Float16*)(smem + 35840);          // [2][64][40]
    _Float16* P_s  = (_Float16*)(smem + 25600);          // [2][64][72] (alias q/k)
    _Float16* vt_s = (_Float16*)(smem + 46080);          // [2][32][72]
    _Float16* oh_s = (_Float16*)(smem + 46080);          // [64][72]   (alias vt)

    const int tid  = threadIdx.x;
    const int wave = tid >> 6;
    const int lane = tid & 63;
    const int l15  = lane & 15;
    const int quad = lane >> 4;

    const int bid = blockIdx.x;
    const int wz = bid & 15, wy = (bid >> 4) & 15, wx = bid >> 8;

    // ---- Phase 0: gather window (with cyclic shift) -> h_s as f16 ----
    {
        const int p  = tid & 1;          // z-pair index (tokens 2p,2p+1)
        const int r  = (tid >> 1) & 15;  // i = r>>2, j = r&3
        const int cb = tid >> 5;         // 0..7
        const int i = r >> 2, j = r & 3;
        const int xg = (wx*4 + i + 2) & 63;
        const int yg = (wy*4 + j + 2) & 63;
        const int zg = (wz*4 + 2 + 2*p) & 63;   // always even, never 63 -> no wrap in pair
        const int tok = r*4 + 2*p;
        const size_t sbase = ((size_t)xg*64 + (size_t)yg)*64 + (size_t)zg;
#pragma unroll
        for (int t = 0; t < 24; ++t) {
            int c = cb + 8*t;
            float2 v = *(const float2*)(x + (size_t)c*V_ELEMS + sbase);
            h_s[tok*H_STRIDE + c]     = (_Float16)v.x;
            h_s[(tok+1)*H_STRIDE + c] = (_Float16)v.y;
        }
    }
    __syncthreads();

    f32x4 out_acc[3][4];
#pragma unroll
    for (int a = 0; a < 3; ++a)
#pragma unroll
        for (int b = 0; b < 4; ++b)
            out_acc[a][b] = (f32x4){0.f, 0.f, 0.f, 0.f};

    const f32x4 fzero = {0.f, 0.f, 0.f, 0.f};

    for (int hp = 0; hp < 3; ++hp) {   // head pair: heads 2hp, 2hp+1
        // ---- Phase A: qkv GEMM for this head pair ----
#pragma unroll
        for (int tt = 0; tt < 3; ++tt) {
            const int t  = wave + 4*tt;       // 0..11
            const int wh = t >> 2;            // 0=q 1=k 2=v
            const int hh = (t >> 1) & 1;      // head within pair
            const int dh = t & 1;             // dim half
            const int n  = wh*192 + (2*hp + hh)*32 + dh*16 + l15;
            f16x8 bfr[6];
#pragma unroll
            for (int ks = 0; ks < 6; ++ks) {
                const float* wp = qkv_w + (size_t)n*192 + ks*32 + quad*8;
                float4 w0 = *(const float4*)wp;
                float4 w1 = *(const float4*)(wp + 4);
                f16x8 bf;
                bf[0]=(_Float16)w0.x; bf[1]=(_Float16)w0.y; bf[2]=(_Float16)w0.z; bf[3]=(_Float16)w0.w;
                bf[4]=(_Float16)w1.x; bf[5]=(_Float16)w1.y; bf[6]=(_Float16)w1.z; bf[7]=(_Float16)w1.w;
                bfr[ks] = bf;
            }
            const float bias = qkv_b[n];
#pragma unroll
            for (int rt = 0; rt < 4; ++rt) {
                f32x4 acc = fzero;
#pragma unroll
                for (int ks = 0; ks < 6; ++ks) {
                    f16x8 af = *(const f16x8*)(h_s + (rt*16 + l15)*H_STRIDE + ks*32 + quad*8);
                    acc = __builtin_amdgcn_mfma_f32_16x16x32_f16(af, bfr[ks], acc, 0, 0, 0);
                }
                if (wh == 2) {
                    // v: transposed store, 4 consecutive tokens -> one b64
                    f16x4 pk;
#pragma unroll
                    for (int r2 = 0; r2 < 4; ++r2) pk[r2] = (_Float16)(acc[r2] + bias);
                    *(f16x4*)(vt_s + (hh*32 + dh*16 + l15)*VT_STRIDE + rt*16 + quad*4) = pk;
                } else {
                    _Float16* dst = (wh == 0 ? q_s : k_s) + hh*2560;
#pragma unroll
                    for (int r2 = 0; r2 < 4; ++r2)
                        dst[(rt*16 + quad*4 + r2)*QK_STRIDE + dh*16 + l15] = (_Float16)(acc[r2] + bias);
                }
            }
        }
        __syncthreads();   // q/k/vt ready

        // ---- Phase B: S = q k^T, softmax (wave handles row-tile rt=wave, both heads) ----
        f32x4 pfr[2][4];
#pragma unroll
        for (int jj = 0; jj < 2; ++jj) {
            f16x8 aq = *(const f16x8*)(q_s + jj*2560 + (wave*16 + l15)*QK_STRIDE + quad*8);
            f32x4 s[4];
#pragma unroll
            for (int ct = 0; ct < 4; ++ct) {
                f16x8 bk = *(const f16x8*)(k_s + jj*2560 + (ct*16 + l15)*QK_STRIDE + quad*8);
                s[ct] = __builtin_amdgcn_mfma_f32_16x16x32_f16(aq, bk, fzero, 0, 0, 0);
            }
            float mx[4];
#pragma unroll
            for (int r = 0; r < 4; ++r) {
                float m = fmaxf(fmaxf(s[0][r], s[1][r]), fmaxf(s[2][r], s[3][r]));
#pragma unroll
                for (int msk = 1; msk < 16; msk <<= 1) m = fmaxf(m, __shfl_xor(m, msk));
                mx[r] = m;
            }
            const float kscale = 0.17677669529663687f * 1.4426950408889634f; // hd^-0.5 * log2(e)
#pragma unroll
            for (int ct = 0; ct < 4; ++ct)
#pragma unroll
                for (int r = 0; r < 4; ++r)
                    s[ct][r] = exp2f((s[ct][r] - mx[r]) * kscale);
#pragma unroll
            for (int r = 0; r < 4; ++r) {
                float sum = s[0][r] + s[1][r] + s[2][r] + s[3][r];
#pragma unroll
                for (int msk = 1; msk < 16; msk <<= 1) sum += __shfl_xor(sum, msk);
                const float inv = 1.0f / sum;
#pragma unroll
                for (int ct = 0; ct < 4; ++ct) s[ct][r] *= inv;
            }
#pragma unroll
            for (int ct = 0; ct < 4; ++ct) pfr[jj][ct] = s[ct];
        }
        __syncthreads();   // all waves done reading q/k -> P may overwrite

        // write P (C-layout -> row-major); each wave reads back only its own rows
#pragma unroll
        for (int jj = 0; jj < 2; ++jj)
#pragma unroll
            for (int ct = 0; ct < 4; ++ct)
#pragma unroll
                for (int r = 0; r < 4; ++r)
                    P_s[(jj*64 + wave*16 + quad*4 + r)*P_STRIDE + ct*16 + l15] =
                        (_Float16)pfr[jj][ct][r];

        // ---- Phase C: O = P V ----
        f32x4 oacc[2][2];
#pragma unroll
        for (int jj = 0; jj < 2; ++jj)
#pragma unroll
            for (int ct = 0; ct < 2; ++ct) oacc[jj][ct] = fzero;
#pragma unroll
        for (int jj = 0; jj < 2; ++jj)
#pragma unroll
            for (int ks = 0; ks < 2; ++ks) {
                f16x8 ap = *(const f16x8*)(P_s + (jj*64 + wave*16 + l15)*P_STRIDE + ks*32 + quad*8);
#pragma unroll
                for (int ct = 0; ct < 2; ++ct) {
                    f16x8 bv = *(const f16x8*)(vt_s + (jj*32 + ct*16 + l15)*VT_STRIDE + ks*32 + quad*8);
                    oacc[jj][ct] = __builtin_amdgcn_mfma_f32_16x16x32_f16(ap, bv, oacc[jj][ct], 0, 0, 0);
                }
            }
        __syncthreads();   // PV done reading vt -> oh may overwrite

#pragma unroll
        for (int jj = 0; jj < 2; ++jj)
#pragma unroll
            for (int ct = 0; ct < 2; ++ct)
#pragma unroll
                for (int r = 0; r < 4; ++r)
                    oh_s[(wave*16 + quad*4 + r)*OH_STRIDE + jj*32 + ct*16 + l15] =
                        (_Float16)oacc[jj][ct][r];
        __syncthreads();   // oh complete

        // ---- Phase D: proj partial-K accumulate (K slice = this pair's 64 dims) ----
        f16x8 afr[4][2];
#pragma unroll
        for (int rt = 0; rt < 4; ++rt)
#pragma unroll
            for (int ks = 0; ks < 2; ++ks)
                afr[rt][ks] = *(const f16x8*)(oh_s + (rt*16 + l15)*OH_STRIDE + ks*32 + quad*8);
#pragma unroll
        for (int cti = 0; cti < 3; ++cti) {
            const int n = (wave + 4*cti)*16 + l15;
#pragma unroll
            for (int ks = 0; ks < 2; ++ks) {
                const float* wp = proj_w + (size_t)n*192 + hp*64 + ks*32 + quad*8;
                float4 w0 = *(const float4*)wp;
                float4 w1 = *(const float4*)(wp + 4);
                f16x8 bf;
                bf[0]=(_Float16)w0.x; bf[1]=(_Float16)w0.y; bf[2]=(_Float16)w0.z; bf[3]=(_Float16)w0.w;
                bf[4]=(_Float16)w1.x; bf[5]=(_Float16)w1.y; bf[6]=(_Float16)w1.z; bf[7]=(_Float16)w1.w;
#pragma unroll
                for (int rt = 0; rt < 4; ++rt)
                    out_acc[cti][rt] =
                        __builtin_amdgcn_mfma_f32_16x16x32_f16(afr[rt][ks], bf, out_acc[cti][rt], 0, 0, 0);
            }
        }
        __syncthreads();   // next iter overwrites q/k (alias P) and vt (alias oh)
    }

    // ---- Epilogue: +bias, scatter (inverse shift) as two aligned float2 per 4-token z-run ----
    {
        const int zA = wz*4 + 2;          // tokens z=0,1 (max 62 -> no wrap)
        const int zB = (wz*4 + 4) & 63;   // tokens z=2,3 (wraps only as full pair)
        const int yg = (wy*4 + quad + 2) & 63;
#pragma unroll
        for (int cti = 0; cti < 3; ++cti) {
            const int n = (wave + 4*cti)*16 + l15;
            const float bias = proj_b[n];
#pragma unroll
            for (int rt = 0; rt < 4; ++rt) {
                const int xg = (wx*4 + rt + 2) & 63;
                const size_t base = (((size_t)n*64 + (size_t)xg)*64 + (size_t)yg)*64;
                float2 v01 = { out_acc[cti][rt][0] + bias, out_acc[cti][rt][1] + bias };
                float2 v23 = { out_acc[cti][rt][2] + bias, out_acc[cti][rt][3] + bias };
                *(float2*)(out + base + zA) = v01;
                *(float2*)(out + base + zB) = v23;
            }
        }
    }
}

extern "C" void kernel_launch(void* const* d_in, const int* in_sizes, int n_in,
                              void* d_out, int out_size, void* d_ws, size_t ws_size,
                              hipStream_t stream) {
    const float* x      = (const float*)d_in[0];
    const float* qkv_w  = (const float*)d_in[1];
    const float* qkv_b  = (const float*)d_in[2];
    const float* proj_w = (const float*)d_in[3];
    const float* proj_b = (const float*)d_in[4];
    float* out = (float*)d_out;
    win_attn_kernel<<<dim3(4096), dim3(256), SMEM_BYTES, stream>>>(
        x, qkv_w, qkv_b, proj_w, proj_b, out);
}

// Round 2
// 804.174 us; speedup vs baseline: 1.2603x; 1.2603x over previous
//
#include <hip/hip_runtime.h>
#include <stdint.h>

#define V_ELEMS (64*64*64)

typedef _Float16 f16x8 __attribute__((ext_vector_type(8)));
typedef _Float16 f16x4 __attribute__((ext_vector_type(4)));
typedef float f32x4 __attribute__((ext_vector_type(4)));

// LDS layout (bytes):
//   h  : [64][200] f16 @ 0      (25600)  token-major window input
//   qk : [2][64][72] f16 @ 25600 (18432) q cols 0-31, k cols 32-63; aliased by P [2][64][72]
//   vt : [2][32][72] f16 @ 44032 (9216)  aliased by oh [64][72]
// total 53248 -> 3 blocks/CU (160K/3 = 53.3K)
#define SMEM_BYTES 53248
#define H_STRIDE 200
#define QKP_STRIDE 72
#define VT_STRIDE 72
#define OH_STRIDE 72

__global__ void cvt_weights_kernel(const float* __restrict__ qkv_w,
                                   const float* __restrict__ proj_w,
                                   _Float16* __restrict__ w16) {
    int i = blockIdx.x * 256 + threadIdx.x;
    if (i < 110592)      w16[i] = (_Float16)qkv_w[i];
    else if (i < 147456) w16[i] = (_Float16)proj_w[i - 110592];
}

__global__ __launch_bounds__(256, 3)
void win_attn_kernel(const float* __restrict__ x,
                     const _Float16* __restrict__ w16,
                     const float* __restrict__ qkv_b,
                     const float* __restrict__ proj_b,
                     float* __restrict__ out)
{
    extern __shared__ char smem[];
    _Float16* h_s  = (_Float16*)smem;                    // [64][200]
    _Float16* qk_s = (_Float16*)(smem + 25600);          // [2][64][72]
    _Float16* P_s  = (_Float16*)(smem + 25600);          // [2][64][72] (alias qk)
    _Float16* vt_s = (_Float16*)(smem + 44032);          // [2][32][72]
    _Float16* oh_s = (_Float16*)(smem + 44032);          // [64][72]   (alias vt)

    const _Float16* qw16 = w16;            // [576][192]
    const _Float16* pw16 = w16 + 110592;   // [192][192]

    const int tid  = threadIdx.x;
    const int wave = tid >> 6;
    const int lane = tid & 63;
    const int l15  = lane & 15;
    const int quad = lane >> 4;

    // XCD-aware swizzle: the 4 wz-partners sharing 64B z-lines get equal bid%8
    // (same XCD under round-robin) and dispatch within delta-bid <= 24.
    const int bid = blockIdx.x;
    const int xcd = bid & 7;
    const int s_  = bid >> 3;
    const int wzl = s_ & 3;
    const int gi  = (s_ >> 2) * 8 + xcd;   // 0..1023 = (wx, wy, wz>>2)
    const int wx  = gi >> 6;
    const int wy  = (gi >> 2) & 15;
    const int wz  = ((gi & 3) << 2) | wzl;

    // ---- Phase 0: gather window (with cyclic shift) -> h_s as f16 ----
    {
        const int p  = tid & 1;          // z-pair index (tokens 2p,2p+1)
        const int r  = (tid >> 1) & 15;  // i = r>>2, j = r&3
        const int cb = tid >> 5;         // 0..7
        const int i = r >> 2, j = r & 3;
        const int xg = (wx*4 + i + 2) & 63;
        const int yg = (wy*4 + j + 2) & 63;
        const int zg = (wz*4 + 2 + 2*p) & 63;   // always even -> no wrap in pair
        const int tok = r*4 + 2*p;
        const size_t sbase = ((size_t)xg*64 + (size_t)yg)*64 + (size_t)zg;
#pragma unroll
        for (int t = 0; t < 24; ++t) {
            int c = cb + 8*t;
            float2 v = *(const float2*)(x + (size_t)c*V_ELEMS + sbase);
            h_s[tok*H_STRIDE + c]     = (_Float16)v.x;
            h_s[(tok+1)*H_STRIDE + c] = (_Float16)v.y;
        }
    }

    f32x4 out_acc[3][4];
#pragma unroll
    for (int a = 0; a < 3; ++a)
#pragma unroll
        for (int b = 0; b < 4; ++b)
            out_acc[a][b] = (f32x4){0.f, 0.f, 0.f, 0.f};

    const f32x4 fzero = {0.f, 0.f, 0.f, 0.f};
    __syncthreads();

#pragma unroll
    for (int hp = 0; hp < 3; ++hp) {   // head pair: heads 2hp, 2hp+1
        // ---- Phase A: qkv GEMM for this head pair ----
#pragma unroll
        for (int tt = 0; tt < 3; ++tt) {
            const int t  = wave + 4*tt;       // 0..11
            const int wh = t >> 2;            // 0=q 1=k 2=v
            const int hh = (t >> 1) & 1;      // head within pair
            const int dh = t & 1;             // dim half
            const int n  = wh*192 + (2*hp + hh)*32 + dh*16 + l15;
            f16x8 bfr[6];
#pragma unroll
            for (int ks = 0; ks < 6; ++ks)
                bfr[ks] = *(const f16x8*)(qw16 + (size_t)n*192 + ks*32 + quad*8);
            const float bias = qkv_b[n];
#pragma unroll
            for (int rt = 0; rt < 4; ++rt) {
                f32x4 acc = fzero;
#pragma unroll
                for (int ks = 0; ks < 6; ++ks) {
                    f16x8 af = *(const f16x8*)(h_s + (rt*16 + l15)*H_STRIDE + ks*32 + quad*8);
                    acc = __builtin_amdgcn_mfma_f32_16x16x32_f16(af, bfr[ks], acc, 0, 0, 0);
                }
                if (wh == 2) {
                    // v: transposed store, 4 consecutive tokens -> one b64
                    f16x4 pk;
#pragma unroll
                    for (int r2 = 0; r2 < 4; ++r2) pk[r2] = (_Float16)(acc[r2] + bias);
                    *(f16x4*)(vt_s + (hh*32 + dh*16 + l15)*VT_STRIDE + rt*16 + quad*4) = pk;
                } else {
                    _Float16* dst = qk_s + hh*64*QKP_STRIDE + (wh == 1 ? 32 : 0);
#pragma unroll
                    for (int r2 = 0; r2 < 4; ++r2)
                        dst[(rt*16 + quad*4 + r2)*QKP_STRIDE + dh*16 + l15] = (_Float16)(acc[r2] + bias);
                }
            }
        }
        __syncthreads();   // q/k/vt ready

        // ---- Phase B: S = q k^T, softmax (wave handles row-tile rt=wave, both heads) ----
        f32x4 pfr[2][4];
#pragma unroll
        for (int jj = 0; jj < 2; ++jj) {
            f16x8 aq = *(const f16x8*)(qk_s + (jj*64 + wave*16 + l15)*QKP_STRIDE + quad*8);
            f32x4 s[4];
#pragma unroll
            for (int ct = 0; ct < 4; ++ct) {
                f16x8 bk = *(const f16x8*)(qk_s + (jj*64 + ct*16 + l15)*QKP_STRIDE + 32 + quad*8);
                s[ct] = __builtin_amdgcn_mfma_f32_16x16x32_f16(aq, bk, fzero, 0, 0, 0);
            }
            float mx[4];
#pragma unroll
            for (int r = 0; r < 4; ++r) {
                float m = fmaxf(fmaxf(s[0][r], s[1][r]), fmaxf(s[2][r], s[3][r]));
#pragma unroll
                for (int msk = 1; msk < 16; msk <<= 1) m = fmaxf(m, __shfl_xor(m, msk));
                mx[r] = m;
            }
            const float kscale = 0.17677669529663687f * 1.4426950408889634f; // hd^-0.5 * log2(e)
#pragma unroll
            for (int ct = 0; ct < 4; ++ct)
#pragma unroll
                for (int r = 0; r < 4; ++r)
                    s[ct][r] = exp2f((s[ct][r] - mx[r]) * kscale);
#pragma unroll
            for (int r = 0; r < 4; ++r) {
                float sum = s[0][r] + s[1][r] + s[2][r] + s[3][r];
#pragma unroll
                for (int msk = 1; msk < 16; msk <<= 1) sum += __shfl_xor(sum, msk);
                const float inv = 1.0f / sum;
#pragma unroll
                for (int ct = 0; ct < 4; ++ct) s[ct][r] *= inv;
            }
#pragma unroll
            for (int ct = 0; ct < 4; ++ct) pfr[jj][ct] = s[ct];
        }
        __syncthreads();   // all waves done reading q/k -> P may overwrite

        // write P (C-layout -> row-major); each wave reads back only its own rows
#pragma unroll
        for (int jj = 0; jj < 2; ++jj)
#pragma unroll
            for (int ct = 0; ct < 4; ++ct)
#pragma unroll
                for (int r = 0; r < 4; ++r)
                    P_s[(jj*64 + wave*16 + quad*4 + r)*QKP_STRIDE + ct*16 + l15] =
                        (_Float16)pfr[jj][ct][r];

        // ---- Phase C: O = P V  (same-wave LDS RAW -> lgkmcnt, no barrier needed) ----
        f32x4 oacc[2][2];
#pragma unroll
        for (int jj = 0; jj < 2; ++jj)
#pragma unroll
            for (int ct = 0; ct < 2; ++ct) oacc[jj][ct] = fzero;
#pragma unroll
        for (int jj = 0; jj < 2; ++jj)
#pragma unroll
            for (int ks = 0; ks < 2; ++ks) {
                f16x8 ap = *(const f16x8*)(P_s + (jj*64 + wave*16 + l15)*QKP_STRIDE + ks*32 + quad*8);
#pragma unroll
                for (int ct = 0; ct < 2; ++ct) {
                    f16x8 bv = *(const f16x8*)(vt_s + (jj*32 + ct*16 + l15)*VT_STRIDE + ks*32 + quad*8);
                    oacc[jj][ct] = __builtin_amdgcn_mfma_f32_16x16x32_f16(ap, bv, oacc[jj][ct], 0, 0, 0);
                }
            }
        __syncthreads();   // PV done reading vt -> oh may overwrite

#pragma unroll
        for (int jj = 0; jj < 2; ++jj)
#pragma unroll
            for (int ct = 0; ct < 2; ++ct)
#pragma unroll
                for (int r = 0; r < 4; ++r)
                    oh_s[(wave*16 + quad*4 + r)*OH_STRIDE + jj*32 + ct*16 + l15] =
                        (_Float16)oacc[jj][ct][r];
        __syncthreads();   // oh complete (cross-wave read next)

        // ---- Phase D: proj partial-K accumulate (K slice = this pair's 64 dims) ----
        f16x8 afr[4][2];
#pragma unroll
        for (int rt = 0; rt < 4; ++rt)
#pragma unroll
            for (int ks = 0; ks < 2; ++ks)
                afr[rt][ks] = *(const f16x8*)(oh_s + (rt*16 + l15)*OH_STRIDE + ks*32 + quad*8);
#pragma unroll
        for (int cti = 0; cti < 3; ++cti) {
            const int n = (wave + 4*cti)*16 + l15;
#pragma unroll
            for (int ks = 0; ks < 2; ++ks) {
                f16x8 bf = *(const f16x8*)(pw16 + (size_t)n*192 + hp*64 + ks*32 + quad*8);
#pragma unroll
                for (int rt = 0; rt < 4; ++rt)
                    out_acc[cti][rt] =
                        __builtin_amdgcn_mfma_f32_16x16x32_f16(afr[rt][ks], bf, out_acc[cti][rt], 0, 0, 0);
            }
        }
        __syncthreads();   // next iter overwrites qk (alias P) and vt (alias oh)
    }

    // ---- Epilogue: +bias, scatter (inverse shift) as two aligned float2 per 4-token z-run ----
    {
        const int zA = wz*4 + 2;          // tokens z=0,1 (max 62 -> no wrap)
        const int zB = (wz*4 + 4) & 63;   // tokens z=2,3 (wraps only as full pair)
        const int yg = (wy*4 + quad + 2) & 63;
#pragma unroll
        for (int cti = 0; cti < 3; ++cti) {
            const int n = (wave + 4*cti)*16 + l15;
            const float bias = proj_b[n];
#pragma unroll
            for (int rt = 0; rt < 4; ++rt) {
                const int xg = (wx*4 + rt + 2) & 63;
                const size_t base = (((size_t)n*64 + (size_t)xg)*64 + (size_t)yg)*64;
                float2 v01 = { out_acc[cti][rt][0] + bias, out_acc[cti][rt][1] + bias };
                float2 v23 = { out_acc[cti][rt][2] + bias, out_acc[cti][rt][3] + bias };
                *(float2*)(out + base + zA) = v01;
                *(float2*)(out + base + zB) = v23;
            }
        }
    }
}

extern "C" void kernel_launch(void* const* d_in, const int* in_sizes, int n_in,
                              void* d_out, int out_size, void* d_ws, size_t ws_size,
                              hipStream_t stream) {
    const float* x      = (const float*)d_in[0];
    const float* qkv_w  = (const float*)d_in[1];
    const float* qkv_b  = (const float*)d_in[2];
    const float* proj_w = (const float*)d_in[3];
    const float* proj_b = (const float*)d_in[4];
    float* out = (float*)d_out;
    _Float16* w16 = (_Float16*)d_ws;   // 147456 f16 = 294912 B

    cvt_weights_kernel<<<dim3(576), dim3(256), 0, stream>>>(qkv_w, proj_w, w16);
    win_attn_kernel<<<dim3(4096), dim3(256), SMEM_BYTES, stream>>>(
        x, w16, qkv_b, proj_b, out);
}